// Round 1
// baseline (439.384 us; speedup 1.0000x reference)
//
#include <hip/hip_runtime.h>

// CatGWRegression on MI355X — fused GAT + GATW + regression head.
// Pipeline:
//  k1_proj : p = x@Wp1 (bf16, stored transposed p_T[c][j]), skipb = x@Wskip1+bias1,
//            s_src/s_tgt row scores (fused epilogue reductions)
//  k3_attn : flash-style masked softmax attention, e-weights computed directly in
//            MFMA A-frag layout, B-frags loaded from global p_T. No LDS/barriers.
//            Epilogue: normalize, +skip, elu -> overwrites skipb (out_elu).
//  k4a     : va = Wp2@a_src2, vb = Wp2@a_tgt2 (p2 eliminated by associativity)
//  k4b     : ss = out_elu@va, st = out_elu@vb
//  k5_msw  : msw = relu(ss_i+st_j)*sw -> d_out (output 2)
//  k6_gemm1: tmp1 = msw@W1 (k-split 8, atomicAdd, fp32 VALU)
//  k7_head : beta = lrelu((tmp1+b1)@W2+b2)@W3+b3)*ols, y_hat = sum(beta*vx)

#define NN 4096
#define FF 128
#define DD2 256
#define NH1 96

typedef __attribute__((ext_vector_type(8))) short bf16x8;
typedef __attribute__((ext_vector_type(4))) float f32x4;

__device__ __forceinline__ short f2bf(float f) {
  unsigned u = __float_as_uint(f);
  u = u + 0x7FFFu + ((u >> 16) & 1u);   // RNE
  return (short)(u >> 16);
}

// ---------------------------------------------------------------- k1
// grid 256, block 256. Block handles 16 rows x all 256 cols; K=128 streamed.
// Weights read from global (L2-hot across blocks), x tile staged in LDS.
__global__ __launch_bounds__(256) void k1_proj(
    const float* __restrict__ x, const float* __restrict__ Wp1,
    const float* __restrict__ Wsk, const float* __restrict__ bias1,
    const float* __restrict__ as1, const float* __restrict__ at1,
    short* __restrict__ pT, float* __restrict__ skipb,
    float* __restrict__ s_src, float* __restrict__ s_tgt)
{
  __shared__ float xs[16][FF];
  const int t = threadIdx.x;
  const int r0 = blockIdx.x * 16;
  for (int i = t; i < 16 * FF; i += 256)
    xs[i >> 7][i & 127] = x[(size_t)r0 * FF + i];
  __syncthreads();

  const int c = t;
  float accp[16], accs[16];
#pragma unroll
  for (int i = 0; i < 16; ++i) { accp[i] = 0.f; accs[i] = 0.f; }

  for (int k = 0; k < FF; k += 4) {
    float wp[4], wk[4];
#pragma unroll
    for (int u = 0; u < 4; ++u) {
      wp[u] = Wp1[(size_t)(k + u) * DD2 + c];
      wk[u] = Wsk[(size_t)(k + u) * DD2 + c];
    }
#pragma unroll
    for (int rr = 0; rr < 16; ++rr) {
      const float4 xv = *(const float4*)&xs[rr][k];  // uniform addr -> LDS broadcast
      accp[rr] += xv.x * wp[0] + xv.y * wp[1] + xv.z * wp[2] + xv.w * wp[3];
      accs[rr] += xv.x * wk[0] + xv.y * wk[1] + xv.z * wk[2] + xv.w * wk[3];
    }
  }

  const float asv = as1[t], atv = at1[t];  // a_src1[h][f], t = h*64+f
  const float bv = bias1[c];
  const int h = t >> 6;
  const int lane = t & 63;

#pragma unroll
  for (int rr = 0; rr < 16; ++rr)
    skipb[(size_t)(r0 + rr) * DD2 + c] = accs[rr] + bv;

  {  // p_T bf16, packed pair stores (column of p = row of p_T, contiguous in j)
    unsigned* dst = (unsigned*)(pT + (size_t)c * NN + r0);
#pragma unroll
    for (int rr = 0; rr < 16; rr += 2) {
      unsigned lo = (unsigned short)f2bf(accp[rr]);
      unsigned hi = (unsigned short)f2bf(accp[rr + 1]);
      dst[rr >> 1] = lo | (hi << 16);
    }
  }

#pragma unroll
  for (int rr = 0; rr < 16; ++rr) {  // s_src[h][i], s_tgt[h][i]
    float ps = accp[rr] * asv, pt = accp[rr] * atv;
#pragma unroll
    for (int off = 32; off > 0; off >>= 1) {
      ps += __shfl_down(ps, off);
      pt += __shfl_down(pt, off);
    }
    if (lane == 0) { s_src[h * NN + r0 + rr] = ps; s_tgt[h * NN + r0 + rr] = pt; }
  }
}

// ---------------------------------------------------------------- k3
// grid 256, block 256 (wave = head). 16 target rows per block.
// Single pass over j: e = mask ? exp(lrelu(s_src+s_tgt)) : 0, computed per-lane
// directly in A-frag layout (m=lane&15 row, k=(lane>>4)*8+u); B-frags (p_T bf16)
// loaded from global. Unnormalized accumulate + l-sum, normalize at end.
__global__ __launch_bounds__(256) void k3_attn(
    const short* __restrict__ pT, const float* __restrict__ s_src,
    const float* __restrict__ s_tgt, const float* __restrict__ sw,
    float* __restrict__ io /* in: skip+bias, out: elu(out) */)
{
  const int t = threadIdx.x;
  const int lane = t & 63;
  const int h = t >> 6;
  const int m = lane & 15;
  const int q = lane >> 4;
  const int i0 = blockIdx.x * 16;

  const float ssrc = s_src[h * NN + i0 + m];
  const float* stg = s_tgt + h * NN;
  const float* swrow = sw + (size_t)(i0 + m) * NN;
  const short* pbase = pT + (size_t)(h * 64 + m) * NN;

  f32x4 acc0 = {0.f, 0.f, 0.f, 0.f};
  f32x4 acc1 = acc0, acc2 = acc0, acc3 = acc0;
  float lsum = 0.f;

  for (int jt = 0; jt < NN; jt += 32) {
    const int jb = jt + q * 8;
    const float4 t0 = *(const float4*)(stg + jb);
    const float4 t1 = *(const float4*)(stg + jb + 4);
    const float4 w0 = *(const float4*)(swrow + jb);
    const float4 w1 = *(const float4*)(swrow + jb + 4);
    const float tj[8] = {t0.x, t0.y, t0.z, t0.w, t1.x, t1.y, t1.z, t1.w};
    const float wv[8] = {w0.x, w0.y, w0.z, w0.w, w1.x, w1.y, w1.z, w1.w};
    bf16x8 af;
    float esum = 0.f;
#pragma unroll
    for (int u = 0; u < 8; ++u) {
      float s = ssrc + tj[u];
      s = fmaxf(s, 0.2f * s);              // leaky_relu(0.2)
      float e = __expf(s);
      e = (wv[u] > 0.f) ? e : 0.f;         // mask: spatial_weights > 0
      esum += e;
      af[u] = f2bf(e);
    }
    lsum += esum;
    const bf16x8 b0 = *(const bf16x8*)(pbase + jb);
    const bf16x8 b1 = *(const bf16x8*)(pbase + 16 * NN + jb);
    const bf16x8 b2 = *(const bf16x8*)(pbase + 32 * NN + jb);
    const bf16x8 b3 = *(const bf16x8*)(pbase + 48 * NN + jb);
    acc0 = __builtin_amdgcn_mfma_f32_16x16x32_bf16(af, b0, acc0, 0, 0, 0);
    acc1 = __builtin_amdgcn_mfma_f32_16x16x32_bf16(af, b1, acc1, 0, 0, 0);
    acc2 = __builtin_amdgcn_mfma_f32_16x16x32_bf16(af, b2, acc2, 0, 0, 0);
    acc3 = __builtin_amdgcn_mfma_f32_16x16x32_bf16(af, b3, acc3, 0, 0, 0);
  }

  // l per row: reduce the 4 quads, then fetch l for C-frag rows (q*4+g)
  lsum += __shfl_xor(lsum, 16);
  lsum += __shfl_xor(lsum, 32);
  float linv[4];
#pragma unroll
  for (int g = 0; g < 4; ++g) linv[g] = 1.0f / __shfl(lsum, q * 4 + g);

  const f32x4 accs[4] = {acc0, acc1, acc2, acc3};
#pragma unroll
  for (int sub = 0; sub < 4; ++sub) {
    const int cg = h * 64 + sub * 16 + m;  // C col = lane&15
#pragma unroll
    for (int g = 0; g < 4; ++g) {
      const int r = i0 + q * 4 + g;        // C row = quad*4+reg
      float z = accs[sub][g] * linv[g] + io[(size_t)r * DD2 + cg];
      z = (z > 0.f) ? z : (__expf(z) - 1.f);   // elu
      io[(size_t)r * DD2 + cg] = z;
    }
  }
}

// ---------------------------------------------------------------- k4a
// va = Wp2 @ a_src2, vb = Wp2 @ a_tgt2. grid 64, block 256 (wave per row).
__global__ __launch_bounds__(256) void k4a_vab(
    const float* __restrict__ Wp2, const float* __restrict__ as2,
    const float* __restrict__ at2, float* __restrict__ va, float* __restrict__ vb)
{
  const int lane = threadIdx.x & 63;
  const int w = threadIdx.x >> 6;
  const int r = blockIdx.x * 4 + w;
  const float4 wv = *(const float4*)(Wp2 + (size_t)r * DD2 + lane * 4);
  const float4 a = *(const float4*)(as2 + lane * 4);
  const float4 b = *(const float4*)(at2 + lane * 4);
  float ps = wv.x * a.x + wv.y * a.y + wv.z * a.z + wv.w * a.w;
  float pt = wv.x * b.x + wv.y * b.y + wv.z * b.z + wv.w * b.w;
#pragma unroll
  for (int off = 32; off > 0; off >>= 1) {
    ps += __shfl_down(ps, off);
    pt += __shfl_down(pt, off);
  }
  if (lane == 0) { va[r] = ps; vb[r] = pt; }
}

// ---------------------------------------------------------------- k4b
// ss[n] = out_elu[n]·va, st[n] = out_elu[n]·vb. grid 1024, wave per row.
__global__ __launch_bounds__(256) void k4b_sst(
    const float* __restrict__ oe, const float* __restrict__ va,
    const float* __restrict__ vb, float* __restrict__ ss, float* __restrict__ st)
{
  const int lane = threadIdx.x & 63;
  const int w = threadIdx.x >> 6;
  const int r = blockIdx.x * 4 + w;
  const float4 ov = *(const float4*)(oe + (size_t)r * DD2 + lane * 4);
  const float4 a = *(const float4*)(va + lane * 4);
  const float4 b = *(const float4*)(vb + lane * 4);
  float ps = ov.x * a.x + ov.y * a.y + ov.z * a.z + ov.w * a.w;
  float pt = ov.x * b.x + ov.y * b.y + ov.z * b.z + ov.w * b.w;
#pragma unroll
  for (int off = 32; off > 0; off >>= 1) {
    ps += __shfl_down(ps, off);
    pt += __shfl_down(pt, off);
  }
  if (lane == 0) { ss[r] = ps; st[r] = pt; }
}

// ---------------------------------------------------------------- k5
// msw = relu(ss_i + st_j) * sw. grid 16384, float4 per thread.
__global__ __launch_bounds__(256) void k5_msw(
    const float* __restrict__ ss, const float* __restrict__ st,
    const float* __restrict__ sw, float* __restrict__ msw)
{
  const size_t gid = (size_t)blockIdx.x * 256 + threadIdx.x;
  const int i = (int)(gid >> 10);
  const int j = (int)(gid & 1023) * 4;
  const float s = ss[i];
  const float4 tv = *(const float4*)(st + j);
  const float4 wv = *(const float4*)(sw + (size_t)i * NN + j);
  float4 r;
  r.x = fmaxf(s + tv.x, 0.f) * wv.x;
  r.y = fmaxf(s + tv.y, 0.f) * wv.y;
  r.z = fmaxf(s + tv.z, 0.f) * wv.z;
  r.w = fmaxf(s + tv.w, 0.f) * wv.w;
  *(float4*)(msw + (size_t)i * NN + j) = r;
}

// ---------------------------------------------------------------- k6
// tmp1 = msw @ W1, M=4096 N=96 K=4096, k-split 8 + atomicAdd.
// block 192 threads: c = t%96, half = t/96 (8 rows each of a 16-row tile).
__global__ __launch_bounds__(192) void k6_gemm1(
    const float* __restrict__ msw, const float* __restrict__ W1g,
    float* __restrict__ tmp1)
{
  __shared__ float ms[16][64];
  const int t = threadIdx.x;
  const int rb = blockIdx.x >> 3;
  const int kb = blockIdx.x & 7;
  const int r0 = rb * 16;
  const int k0 = kb * 512;
  const int c = t % 96;
  const int half = t / 96;
  float acc[8];
#pragma unroll
  for (int i = 0; i < 8; ++i) acc[i] = 0.f;

  for (int kt = k0; kt < k0 + 512; kt += 64) {
    __syncthreads();
    for (int i = t; i < 1024; i += 192)
      ms[i >> 6][i & 63] = msw[(size_t)(r0 + (i >> 6)) * NN + kt + (i & 63)];
    __syncthreads();
    for (int kk = 0; kk < 64; kk += 4) {
      const float b0 = W1g[(size_t)(kt + kk) * NH1 + c];
      const float b1 = W1g[(size_t)(kt + kk + 1) * NH1 + c];
      const float b2 = W1g[(size_t)(kt + kk + 2) * NH1 + c];
      const float b3 = W1g[(size_t)(kt + kk + 3) * NH1 + c];
#pragma unroll
      for (int rr = 0; rr < 8; ++rr) {
        const float4 av = *(const float4*)&ms[half * 8 + rr][kk];  // broadcast
        acc[rr] += av.x * b0 + av.y * b1 + av.z * b2 + av.w * b3;
      }
    }
  }
#pragma unroll
  for (int rr = 0; rr < 8; ++rr)
    atomicAdd(&tmp1[(size_t)(r0 + half * 8 + rr) * NH1 + c], acc[rr]);
}

// ---------------------------------------------------------------- k7
// beta/y_hat head. grid 512 (8 rows/block), block 256.
__global__ __launch_bounds__(256) void k7_head(
    const float* __restrict__ tmp1, const float* __restrict__ b1,
    const float* __restrict__ W2, const float* __restrict__ b2,
    const float* __restrict__ W3, const float* __restrict__ b3,
    const float* __restrict__ ols, const float* __restrict__ vx,
    float* __restrict__ beta, float* __restrict__ yhat)
{
  __shared__ float w2s[96][32];
  __shared__ float w3s[32][16];
  __shared__ float t1s[8][96];
  __shared__ float t2s[8][33];
  const int t = threadIdx.x;
  const int r0 = blockIdx.x * 8;
  for (int i = t; i < 96 * 32; i += 256) w2s[i >> 5][i & 31] = W2[i];
  for (int i = t; i < 32 * 16; i += 256) w3s[i >> 4][i & 15] = W3[i];
  for (int i = t; i < 8 * 96; i += 256) {
    const int rr = i / 96, k = i - rr * 96;
    t1s[rr][k] = tmp1[(size_t)(r0 + rr) * 96 + k] + b1[k];
  }
  __syncthreads();
  {
    const int rr = t >> 5, c2 = t & 31;
    float a = b2[c2];
    for (int k = 0; k < 96; ++k) a += t1s[rr][k] * w2s[k][c2];
    t2s[rr][c2] = a;
  }
  __syncthreads();
  const int rr = t >> 5;
  const int v = t & 31;
  if (v < 16) {
    float z = b3[v];
#pragma unroll
    for (int k = 0; k < 32; ++k) z += t2s[rr][k] * w3s[k][v];
    z = fmaxf(z, 0.2f * z);               // leaky_relu(0.2)
    const float bvv = z * ols[v];
    const int r = r0 + rr;
    beta[(size_t)r * 16 + v] = bvv;
    float yv = bvv * vx[(size_t)r * 16 + v];
    yv += __shfl_down(yv, 8);
    yv += __shfl_down(yv, 4);
    yv += __shfl_down(yv, 2);
    yv += __shfl_down(yv, 1);
    if (v == 0) yhat[r] = yv;
  }
}

// ---------------------------------------------------------------- launch
// ws layout (bytes)
#define OFF_PT    0u
#define OFF_SKIPB 2097152u
#define OFF_SSRC  6291456u
#define OFF_STGT  6356992u
#define OFF_VA    6422528u
#define OFF_VB    6423552u
#define OFF_SS    6424576u
#define OFF_ST    6440960u
#define OFF_TMP1  6457344u
// d_out layout (floats)
#define OUT_YHAT 65536
#define OUT_MSW  69632

extern "C" void kernel_launch(void* const* d_in, const int* in_sizes, int n_in,
                              void* d_out, int out_size, void* d_ws, size_t ws_size,
                              hipStream_t stream) {
  const float* x    = (const float*)d_in[0];
  // d_in[1] edge_distances: unused by the reference
  const float* sw   = (const float*)d_in[2];
  const float* Wp1  = (const float*)d_in[3];
  const float* as1  = (const float*)d_in[4];
  const float* at1  = (const float*)d_in[5];
  const float* Wsk  = (const float*)d_in[6];
  const float* bias1= (const float*)d_in[7];
  const float* Wp2  = (const float*)d_in[8];
  const float* as2  = (const float*)d_in[9];
  const float* at2  = (const float*)d_in[10];
  const float* W1   = (const float*)d_in[11];
  const float* b1   = (const float*)d_in[12];
  const float* W2   = (const float*)d_in[13];
  const float* b2   = (const float*)d_in[14];
  const float* W3   = (const float*)d_in[15];
  const float* b3   = (const float*)d_in[16];
  const float* ols  = (const float*)d_in[17];
  const float* vx   = (const float*)d_in[18];

  float* out = (float*)d_out;
  char* ws = (char*)d_ws;
  short* pT    = (short*)(ws + OFF_PT);
  float* skipb = (float*)(ws + OFF_SKIPB);   // becomes out_elu in place (k3)
  float* s_src = (float*)(ws + OFF_SSRC);
  float* s_tgt = (float*)(ws + OFF_STGT);
  float* va    = (float*)(ws + OFF_VA);
  float* vb    = (float*)(ws + OFF_VB);
  float* ssv   = (float*)(ws + OFF_SS);
  float* stv   = (float*)(ws + OFF_ST);
  float* tmp1  = (float*)(ws + OFF_TMP1);

  k1_proj<<<256, 256, 0, stream>>>(x, Wp1, Wsk, bias1, as1, at1, pT, skipb, s_src, s_tgt);
  k3_attn<<<256, 256, 0, stream>>>(pT, s_src, s_tgt, sw, skipb);
  k4a_vab<<<64, 256, 0, stream>>>(Wp2, as2, at2, va, vb);
  k4b_sst<<<1024, 256, 0, stream>>>(skipb, va, vb, ssv, stv);
  k5_msw<<<16384, 256, 0, stream>>>(ssv, stv, sw, out + OUT_MSW);
  hipMemsetAsync(tmp1, 0, (size_t)NN * NH1 * sizeof(float), stream);
  k6_gemm1<<<2048, 192, 0, stream>>>(out + OUT_MSW, W1, tmp1);
  k7_head<<<512, 256, 0, stream>>>(tmp1, b1, W2, b2, W3, b3, ols, vx, out, out + OUT_YHAT);
}